// Round 1
// baseline (271.402 us; speedup 1.0000x reference)
//
#include <hip/hip_runtime.h>

#define HH 512
#define WW 512
#define NPIX (HH*WW)      // 2^18
#define BATCH 16
#define NIMG 32           // 16 ref + 16 tgt

typedef unsigned char uchar;
typedef unsigned long long u64;

// ---- Stages 1+2+3+4: barrier-free wave-pipelined strip kernel with fused
// luminance. One wave = 52 output cols x 32 output rows. Rolling register
// pipeline over rows with an explicit 2-row global-load prefetch (pA/pB),
// now fetching 3 RGB channels and combining to luminance at consume time.
// E/hE/p/v as ballot bitmasks; 7-deep moment ring for the vertical window.
// No LDS, no __syncthreads. Lane -> col = sx*52 + lane - 6; outputs lanes 6..57.

__inline__ __device__ float wave_reduce(float v) {
#pragma unroll
    for (int o = 32; o > 0; o >>= 1) v += __shfl_down(v, o);
    return v;
}

__global__ __launch_bounds__(256) void k_strip(const float* __restrict__ ref,
                                               const float* __restrict__ tgt,
                                               uchar* __restrict__ Mo_g,
                                               double* __restrict__ acc) {
    int lane = threadIdx.x & 63;
    int gw = blockIdx.x * 4 + (threadIdx.x >> 6);   // 0..5119
    int img = gw / 160;                             // 10 sx * 16 sy
    int rem = gw - img * 160;
    int sy = rem / 10;
    int sx = rem - sy * 10;
    int r0 = sy << 5;          // first output row
    int c0 = sx * 52;
    int col = c0 + lane - 6;
    bool colok = (unsigned)col < WW;

    // precomputed clamped shuffle source lanes
    int lm1 = (lane > 0) ? lane - 1 : 0;
    int lp1 = (lane < 63) ? lane + 1 : 63;
    int lm2 = (lane > 1) ? lane - 2 : 0;
    int lp2 = (lane < 62) ? lane + 2 : 63;

    const float* base = (img < BATCH) ? (ref + (size_t)img * 3 * NPIX)
                                      : (tgt + (size_t)(img - BATCH) * 3 * NPIX);
    const float* Rp = base;
    const float* Gp = base + NPIX;
    const float* Bp = base + 2 * NPIX;
    uchar* Mo = Mo_g + (size_t)img * NPIX;

    // rolling lum triples: slot0=oldest(L-3) .. slot3=newest(L)
    float tm0 = 0, tm1 = 0, tm2 = 0, tm3 = 0;
    float tc0 = 0, tc1 = 0, tc2 = 0, tc3 = 0;
    float tp0 = 0, tp1 = 0, tp2 = 0, tp3 = 0;
    unsigned eb = 0, hb = 0, pbm = 0, vbm = 0;

    // ---- explicit prefetch pipeline (depth 2), 3 channels per slot ----
    float pAr, pAg, pAb, pBr, pBg, pBb;
#define FETCH3(rr, fr, fg, fb) { \
    bool ok = ((unsigned)(rr) < HH) && colok; \
    size_t off = (size_t)(rr) * WW + col; \
    fr = ok ? Rp[off] : 0.0f; \
    fg = ok ? Gp[off] : 0.0f; \
    fb = ok ? Bp[off] : 0.0f; }

    FETCH3(r0 - 6, pAr, pAg, pAb);
    FETCH3(r0 - 5, pBr, pBg, pBb);

#define LOADROW(Lr) { \
    tm0 = tm1; tc0 = tc1; tp0 = tp1; \
    tm1 = tm2; tc1 = tc2; tp1 = tp2; \
    tm2 = tm3; tc2 = tc3; tp2 = tp3; \
    float ln = 0.299f * pAr + 0.587f * pAg + 0.114f * pAb; \
    pAr = pBr; pAg = pBg; pAb = pBb; \
    FETCH3((Lr) + 2, pBr, pBg, pBb); \
    tc3 = ln; tm3 = __shfl(ln, lm1); tp3 = __shfl(ln, lp1); }

#define SOBEL_E(Lr) { \
    float gx = (tp1 - tm1) + 2.0f * (tp2 - tm2) + (tp3 - tm3); \
    float gy = (tm3 + 2.0f * tc3 + tp3) - (tm1 + 2.0f * tc1 + tp1); \
    float grad = sqrtf(gx * gx + gy * gy + 1e-12f); \
    bool e = (grad > 0.1f) && colok && ((unsigned)((Lr) - 1) < HH); \
    u64 ebal = __ballot(e); \
    eb = (eb << 1) | (e ? 1u : 0u); \
    unsigned hE5 = (unsigned)((ebal << 2) >> lane) & 0x1Fu; \
    hb = (hb << 1) | (hE5 ? 1u : 0u); }

    // ---- pre-roll: rows r0-6, r0-5 ----
    for (int q = 0; q < 2; ++q) { int Lr = r0 - 6 + q; LOADROW(Lr); }
    // ---- warm: rows r0-4..r0-1 (E/hE only) ----
    for (int q = 0; q < 4; ++q) { int Lr = r0 - 4 + q; LOADROW(Lr); SOBEL_E(Lr); }

    // ---- steady: 42 iterations, ring unrolled x7 ----
    float r1p[7], r2p[7], r1v[7], r2v[7];
    unsigned rcn[7];
    unsigned cnt_acc = 0;
    float a1p = 0, a2p = 0, a1v = 0, a2v = 0;
    float c0a = 0, c1a = 0, c2a = 0, c3a = 0;

    for (int o6 = 0; o6 < 6; ++o6) {
#pragma unroll
        for (int u = 0; u < 7; ++u) {
            int j = o6 * 7 + u;
            int Lr = r0 + j;
            LOADROW(Lr);
            SOBEL_E(Lr);
            int m = Lr - 3;
            bool ed = (hb & 0x1Fu) != 0;
            bool e3 = ((eb >> 2) & 1u) != 0;
            bool mrowok = (unsigned)m < HH;
            bool pp = ed && !e3 && mrowok && colok;
            bool vv = (!ed) && mrowok && colok;
            u64 pb = __ballot(pp);
            u64 vb = __ballot(vv);
            pbm = (pbm << 1) | (pp ? 1u : 0u);
            vbm = (vbm << 1) | (vv ? 1u : 0u);

            float xx0 = __shfl(tm0, lm2);   // col-3
            float xx1 = __shfl(tc0, lm2);   // col-2
            float xx2 = tm0;                // col-1
            float xx3 = tc0;                // col
            float xx4 = tp0;                // col+1
            float xx5 = __shfl(tc0, lp2);   // col+2
            float xx6 = __shfl(tp0, lp2);   // col+3
            unsigned pw = (unsigned)((pb << 3) >> lane) & 0x7Fu;
            unsigned vw = (unsigned)((vb << 3) >> lane) & 0x7Fu;
            unsigned cnt_new = (unsigned)__popc(pw) | ((unsigned)__popc(vw) << 8);
            float s1p = 0, s2p = 0, s1v = 0, s2v = 0;
#define TAP(i, xi) { float xq = (xi) * (xi); \
            s1p += ((pw >> (i)) & 1u) ? (xi) : 0.0f; \
            s2p += ((pw >> (i)) & 1u) ? xq : 0.0f; \
            s1v += ((vw >> (i)) & 1u) ? (xi) : 0.0f; \
            s2v += ((vw >> (i)) & 1u) ? xq : 0.0f; }
            TAP(0, xx0) TAP(1, xx1) TAP(2, xx2) TAP(3, xx3)
            TAP(4, xx4) TAP(5, xx5) TAP(6, xx6)
#undef TAP

            if (j >= 7) {   // slide out row m-7
                cnt_acc -= rcn[u];
                a1p -= r1p[u]; a2p -= r2p[u]; a1v -= r1v[u]; a2v -= r2v[u];
            }
            cnt_acc += cnt_new;
            a1p += s1p; a2p += s2p; a1v += s1v; a2v += s2v;
            rcn[u] = cnt_new; r1p[u] = s1p; r2p[u] = s2p; r1v[u] = s1v; r2v[u] = s2v;

            if (j >= 3 && j <= 34) {   // write prox byte for owned row m
                if (lane >= 6 && lane <= 57 && colok)
                    Mo[(size_t)m * WW + col] = (uchar)(pp ? 1 : 0);
            }
            if (j >= 6 && j <= 37) {   // output row y = Lr-6
                float mp0 = (float)((pbm >> 3) & 1u);
                float mb0 = (float)((vbm >> 3) & 1u);
                if (lane < 6 || lane > 57) { mp0 = 0.0f; mb0 = 0.0f; }
                float cpf = (float)(cnt_acc & 0xFFu);
                float cvf = (float)((cnt_acc >> 8) & 0xFFu);
                float rCp = __builtin_amdgcn_rcpf(fmaxf(cpf, 1.0f));
                float meanp = a1p * rCp;
                float varp = fmaxf(a2p * rCp - meanp * meanp, 0.0f);
                float rCb = __builtin_amdgcn_rcpf(fmaxf(cvf, 1.0f));
                float meanb = a1v * rCb;
                float varb = fmaxf(a2v * rCb - meanb * meanb, 0.0f);
                c0a += varp * mp0; c1a += mp0;
                c2a += varb * mb0; c3a += mb0;
            }
        }
    }

    c0a = wave_reduce(c0a); c1a = wave_reduce(c1a);
    c2a = wave_reduce(c2a); c3a = wave_reduce(c3a);
    if (lane == 0) {
        atomicAdd(&acc[img * 4 + 0], (double)c0a);
        atomicAdd(&acc[img * 4 + 1], (double)c1a);
        atomicAdd(&acc[img * 4 + 2], (double)c2a);
        atomicAdd(&acc[img * 4 + 3], (double)c3a);
    }
}

// ---------------- Stage 5: output from prox byte masks + fused flags ----------
// flags computed once per block (thread 0, double precision — identical math to
// the old k_flags kernel) and broadcast via LDS.
__global__ __launch_bounds__(256) void k_out(const uchar4* __restrict__ M,
                                             const double* __restrict__ acc,
                                             float4* __restrict__ out) {
    __shared__ float sf[2];
    int idx = blockIdx.x * 256 + threadIdx.x;   // BATCH * NPIX/4 threads
    int b = idx >> 16;                          // constant within a block
    if (threadIdx.x == 0) {
        const double* a = acc + (size_t)b * 4;
        double vp = a[0] / fmax(a[1], 1.0);
        double vb = a[2] / fmax(a[3], 1.0);
        sf[0] = ((vp / (vb + 1e-12)) > 2.0) ? 1.0f : 0.0f;
        const double* a2 = acc + (size_t)(b + BATCH) * 4;
        double vp2 = a2[0] / fmax(a2[1], 1.0);
        double vb2 = a2[2] / fmax(a2[3], 1.0);
        sf[1] = ((vp2 / (vb2 + 1e-12)) > 2.0) ? 1.0f : 0.0f;
    }
    __syncthreads();
    float fr = sf[0], ft = sf[1];
    int p = idx & 65535;
    uchar4 mr = M[(size_t)b * 65536 + p];
    uchar4 mt = M[(size_t)(b + BATCH) * 65536 + p];
    float4 o;
    o.x = fmaxf((mt.x ? ft : 0.0f) - (mr.x ? fr : 0.0f), 0.0f);
    o.y = fmaxf((mt.y ? ft : 0.0f) - (mr.y ? fr : 0.0f), 0.0f);
    o.z = fmaxf((mt.z ? ft : 0.0f) - (mr.z ? fr : 0.0f), 0.0f);
    o.w = fmaxf((mt.w ? ft : 0.0f) - (mr.w ? fr : 0.0f), 0.0f);
    out[idx] = o;
}

extern "C" void kernel_launch(void* const* d_in, const int* in_sizes, int n_in,
                              void* d_out, int out_size, void* d_ws, size_t ws_size,
                              hipStream_t stream) {
    const float* ref = (const float*)d_in[0];
    const float* tgt = (const float*)d_in[1];
    float* out = (float*)d_out;

    char* ws = (char*)d_ws;
    double* acc = (double*)ws;                       // 32*4 doubles = 1 KB
    uchar* Mo = (uchar*)(ws + 2048);                 // 8 MB prox bytes

    (void)hipMemsetAsync(acc, 0, NIMG * 4 * sizeof(double), stream);

    k_strip<<<1280, 256, 0, stream>>>(ref, tgt, Mo, acc);   // 5120 waves
    k_out<<<BATCH * NPIX / 4 / 256, 256, 0, stream>>>((const uchar4*)Mo, acc, (float4*)out);
}

// Round 3
// 226.219 us; speedup vs baseline: 1.1997x; 1.1997x over previous
//
#include <hip/hip_runtime.h>
#include <hip/hip_cooperative_groups.h>

namespace cg = cooperative_groups;

#define HH 512
#define WW 512
#define NPIX (HH*WW)      // 2^18
#define BATCH 16
#define NIMG 32           // 16 ref + 16 tgt
#define NBLK 1280
#define NTHR (NBLK*256)   // 327680

typedef unsigned char uchar;
typedef unsigned long long u64;

__inline__ __device__ float wave_reduce(float v) {
#pragma unroll
    for (int o = 32; o > 0; o >>= 1) v += __shfl_down(v, o);
    return v;
}

// ---------------- phase 1: luminance (+ acc zeroing), grid-stride ----------
__device__ __forceinline__ void lum_body(int tid, int nthr,
                                         const float* __restrict__ ref,
                                         const float* __restrict__ tgt,
                                         float* __restrict__ lum,
                                         double* __restrict__ acc) {
    if (tid < NIMG * 4) acc[tid] = 0.0;
    const float4* r4 = (const float4*)ref;
    const float4* t4 = (const float4*)tgt;
    float4* l4 = (float4*)lum;
    const int total = NIMG * NPIX / 4;        // 2097152
    for (int idx = tid; idx < total; idx += nthr) {
        int img = idx >> 16;                  // NPIX/4 = 65536
        int p4 = idx & 65535;
        const float4* src = (img < BATCH) ? (r4 + (size_t)img * 3 * 65536)
                                          : (t4 + (size_t)(img - BATCH) * 3 * 65536);
        float4 r = src[p4];
        float4 g = src[65536 + p4];
        float4 b = src[131072 + p4];
        float4 o;
        o.x = 0.299f * r.x + 0.587f * g.x + 0.114f * b.x;
        o.y = 0.299f * r.y + 0.587f * g.y + 0.114f * b.y;
        o.z = 0.299f * r.z + 0.587f * g.z + 0.114f * b.z;
        o.w = 0.299f * r.w + 0.587f * g.w + 0.114f * b.w;
        l4[idx] = o;
    }
}

// ---------------- phase 2: verified round-0 strip body --------------------
// One wave = 52 output cols x 32 output rows. Rolling register pipeline with
// depth-2 global prefetch reading the lum buffer. No LDS, no __syncthreads.
__device__ __forceinline__ void strip_body(const float* __restrict__ lum,
                                           uchar* __restrict__ Mo_g,
                                           double* __restrict__ acc,
                                           int lane, int gw) {
    int img = gw / 160;                             // 10 sx * 16 sy
    int rem = gw - img * 160;
    int sy = rem / 10;
    int sx = rem - sy * 10;
    int r0 = sy << 5;          // first output row
    int c0 = sx * 52;
    int col = c0 + lane - 6;
    bool colok = (unsigned)col < WW;

    int lm1 = (lane > 0) ? lane - 1 : 0;
    int lp1 = (lane < 63) ? lane + 1 : 63;
    int lm2 = (lane > 1) ? lane - 2 : 0;
    int lp2 = (lane < 62) ? lane + 2 : 63;

    const float* Lp = lum + (size_t)img * NPIX;
    uchar* Mo = Mo_g + (size_t)img * NPIX;

    float tm0 = 0, tm1 = 0, tm2 = 0, tm3 = 0;
    float tc0 = 0, tc1 = 0, tc2 = 0, tc3 = 0;
    float tp0 = 0, tp1 = 0, tp2 = 0, tp3 = 0;
    unsigned eb = 0, hb = 0, pbm = 0, vbm = 0;

    float preA = (((unsigned)(r0 - 6) < HH) && colok) ? Lp[(size_t)(r0 - 6) * WW + col] : 0.0f;
    float preB = (((unsigned)(r0 - 5) < HH) && colok) ? Lp[(size_t)(r0 - 5) * WW + col] : 0.0f;

#define LOADROW(Lr) { \
    tm0 = tm1; tc0 = tc1; tp0 = tp1; \
    tm1 = tm2; tc1 = tc2; tp1 = tp2; \
    tm2 = tm3; tc2 = tc3; tp2 = tp3; \
    float ln = preA; preA = preB; \
    { int rr = (Lr) + 2; \
      preB = (((unsigned)rr < HH) && colok) ? Lp[(size_t)rr * WW + col] : 0.0f; } \
    tc3 = ln; tm3 = __shfl(ln, lm1); tp3 = __shfl(ln, lp1); }

#define SOBEL_E(Lr) { \
    float gx = (tp1 - tm1) + 2.0f * (tp2 - tm2) + (tp3 - tm3); \
    float gy = (tm3 + 2.0f * tc3 + tp3) - (tm1 + 2.0f * tc1 + tp1); \
    float grad = sqrtf(gx * gx + gy * gy + 1e-12f); \
    bool e = (grad > 0.1f) && colok && ((unsigned)((Lr) - 1) < HH); \
    u64 ebal = __ballot(e); \
    eb = (eb << 1) | (e ? 1u : 0u); \
    unsigned hE5 = (unsigned)((ebal << 2) >> lane) & 0x1Fu; \
    hb = (hb << 1) | (hE5 ? 1u : 0u); }

    for (int q = 0; q < 2; ++q) { int Lr = r0 - 6 + q; LOADROW(Lr); }
    for (int q = 0; q < 4; ++q) { int Lr = r0 - 4 + q; LOADROW(Lr); SOBEL_E(Lr); }

    float r1p[7], r2p[7], r1v[7], r2v[7];
    unsigned rcn[7];
    unsigned cnt_acc = 0;
    float a1p = 0, a2p = 0, a1v = 0, a2v = 0;
    float c0a = 0, c1a = 0, c2a = 0, c3a = 0;

    for (int o6 = 0; o6 < 6; ++o6) {
#pragma unroll
        for (int u = 0; u < 7; ++u) {
            int j = o6 * 7 + u;
            int Lr = r0 + j;
            LOADROW(Lr);
            SOBEL_E(Lr);
            int m = Lr - 3;
            bool ed = (hb & 0x1Fu) != 0;
            bool e3 = ((eb >> 2) & 1u) != 0;
            bool mrowok = (unsigned)m < HH;
            bool pp = ed && !e3 && mrowok && colok;
            bool vv = (!ed) && mrowok && colok;
            u64 pb = __ballot(pp);
            u64 vb = __ballot(vv);
            pbm = (pbm << 1) | (pp ? 1u : 0u);
            vbm = (vbm << 1) | (vv ? 1u : 0u);

            float xx0 = __shfl(tm0, lm2);   // col-3
            float xx1 = __shfl(tc0, lm2);   // col-2
            float xx2 = tm0;                // col-1
            float xx3 = tc0;                // col
            float xx4 = tp0;                // col+1
            float xx5 = __shfl(tc0, lp2);   // col+2
            float xx6 = __shfl(tp0, lp2);   // col+3
            unsigned pw = (unsigned)((pb << 3) >> lane) & 0x7Fu;
            unsigned vw = (unsigned)((vb << 3) >> lane) & 0x7Fu;
            unsigned cnt_new = (unsigned)__popc(pw) | ((unsigned)__popc(vw) << 8);
            float s1p = 0, s2p = 0, s1v = 0, s2v = 0;
#define TAP(i, xi) { float xq = (xi) * (xi); \
            s1p += ((pw >> (i)) & 1u) ? (xi) : 0.0f; \
            s2p += ((pw >> (i)) & 1u) ? xq : 0.0f; \
            s1v += ((vw >> (i)) & 1u) ? (xi) : 0.0f; \
            s2v += ((vw >> (i)) & 1u) ? xq : 0.0f; }
            TAP(0, xx0) TAP(1, xx1) TAP(2, xx2) TAP(3, xx3)
            TAP(4, xx4) TAP(5, xx5) TAP(6, xx6)
#undef TAP

            if (j >= 7) {   // slide out row m-7
                cnt_acc -= rcn[u];
                a1p -= r1p[u]; a2p -= r2p[u]; a1v -= r1v[u]; a2v -= r2v[u];
            }
            cnt_acc += cnt_new;
            a1p += s1p; a2p += s2p; a1v += s1v; a2v += s2v;
            rcn[u] = cnt_new; r1p[u] = s1p; r2p[u] = s2p; r1v[u] = s1v; r2v[u] = s2v;

            if (j >= 3 && j <= 34) {   // write prox byte for owned row m
                if (lane >= 6 && lane <= 57 && colok)
                    Mo[(size_t)m * WW + col] = (uchar)(pp ? 1 : 0);
            }
            if (j >= 6 && j <= 37) {   // output row y = Lr-6
                float mp0 = (float)((pbm >> 3) & 1u);
                float mb0 = (float)((vbm >> 3) & 1u);
                if (lane < 6 || lane > 57) { mp0 = 0.0f; mb0 = 0.0f; }
                float cpf = (float)(cnt_acc & 0xFFu);
                float cvf = (float)((cnt_acc >> 8) & 0xFFu);
                float rCp = __builtin_amdgcn_rcpf(fmaxf(cpf, 1.0f));
                float meanp = a1p * rCp;
                float varp = fmaxf(a2p * rCp - meanp * meanp, 0.0f);
                float rCb = __builtin_amdgcn_rcpf(fmaxf(cvf, 1.0f));
                float meanb = a1v * rCb;
                float varb = fmaxf(a2v * rCb - meanb * meanb, 0.0f);
                c0a += varp * mp0; c1a += mp0;
                c2a += varb * mb0; c3a += mb0;
            }
        }
    }
#undef LOADROW
#undef SOBEL_E

    c0a = wave_reduce(c0a); c1a = wave_reduce(c1a);
    c2a = wave_reduce(c2a); c3a = wave_reduce(c3a);
    if (lane == 0) {
        atomicAdd(&acc[img * 4 + 0], (double)c0a);
        atomicAdd(&acc[img * 4 + 1], (double)c1a);
        atomicAdd(&acc[img * 4 + 2], (double)c2a);
        atomicAdd(&acc[img * 4 + 3], (double)c3a);
    }
}

// ---------------- phase 3: flags (LDS) + output --------------------------
__device__ __forceinline__ void flags_to_lds(const double* __restrict__ acc,
                                             float* sflags) {
    if (threadIdx.x < NIMG) {
        const double* a = acc + (size_t)threadIdx.x * 4;
        double vp = a[0] / fmax(a[1], 1.0);
        double vb = a[2] / fmax(a[3], 1.0);
        sflags[threadIdx.x] = ((vp / (vb + 1e-12)) > 2.0) ? 1.0f : 0.0f;
    }
    __syncthreads();
}

__device__ __forceinline__ void out_body(int tid, int nthr,
                                         const uchar* __restrict__ Mo_g,
                                         const float* sflags,
                                         float* __restrict__ out) {
    const uchar4* M4 = (const uchar4*)Mo_g;
    float4* o4 = (float4*)out;
    const int total = BATCH * NPIX / 4;   // 1048576
    for (int idx = tid; idx < total; idx += nthr) {
        int b = idx >> 16;
        int p = idx & 65535;
        float fr = sflags[b], ft = sflags[b + BATCH];
        uchar4 mr = M4[(size_t)b * 65536 + p];
        uchar4 mt = M4[(size_t)(b + BATCH) * 65536 + p];
        float4 o;
        o.x = fmaxf((mt.x ? ft : 0.0f) - (mr.x ? fr : 0.0f), 0.0f);
        o.y = fmaxf((mt.y ? ft : 0.0f) - (mr.y ? fr : 0.0f), 0.0f);
        o.z = fmaxf((mt.z ? ft : 0.0f) - (mr.z ? fr : 0.0f), 0.0f);
        o.w = fmaxf((mt.w ? ft : 0.0f) - (mr.w ? fr : 0.0f), 0.0f);
        o4[idx] = o;
    }
}

// ---------------- fused cooperative kernel --------------------------------
// __launch_bounds__(256, 5): force VGPR <= ~102 so the runtime's cooperative
// co-residency validation admits 1280 blocks (5 blocks/CU). Round-2's launch
// was rejected — most likely the unbounded merged kernel exceeded the budget.
__global__ __launch_bounds__(256, 5) void k_fused(const float* __restrict__ ref,
                                                  const float* __restrict__ tgt,
                                                  float* __restrict__ out,
                                                  float* __restrict__ lum,
                                                  uchar* __restrict__ Mo_g,
                                                  double* __restrict__ acc) {
    cg::grid_group grid = cg::this_grid();
    int tid = blockIdx.x * 256 + threadIdx.x;

    lum_body(tid, NTHR, ref, tgt, lum, acc);
    __threadfence();
    grid.sync();
    __threadfence();

    {
        int lane = threadIdx.x & 63;
        int gw = blockIdx.x * 4 + (threadIdx.x >> 6);   // 0..5119
        strip_body(lum, Mo_g, acc, lane, gw);
    }
    __threadfence();
    grid.sync();
    __threadfence();

    __shared__ float sflags[NIMG];
    flags_to_lds(acc, sflags);
    out_body(tid, NTHR, Mo_g, sflags, out);
}

// ---------------- fallback kernels (verified structures) ------------------
__global__ __launch_bounds__(256) void k_lum(const float* __restrict__ ref,
                                             const float* __restrict__ tgt,
                                             float* __restrict__ lum,
                                             double* __restrict__ acc) {
    lum_body(blockIdx.x * 256 + threadIdx.x, gridDim.x * 256, ref, tgt, lum, acc);
}

__global__ __launch_bounds__(256) void k_strip(const float* __restrict__ lum,
                                               uchar* __restrict__ Mo_g,
                                               double* __restrict__ acc) {
    int lane = threadIdx.x & 63;
    int gw = blockIdx.x * 4 + (threadIdx.x >> 6);
    strip_body(lum, Mo_g, acc, lane, gw);
}

__global__ __launch_bounds__(256) void k_out(const uchar* __restrict__ Mo_g,
                                             const double* __restrict__ acc,
                                             float* __restrict__ out) {
    __shared__ float sflags[NIMG];
    flags_to_lds(acc, sflags);
    out_body(blockIdx.x * 256 + threadIdx.x, gridDim.x * 256, Mo_g, sflags, out);
}

extern "C" void kernel_launch(void* const* d_in, const int* in_sizes, int n_in,
                              void* d_out, int out_size, void* d_ws, size_t ws_size,
                              hipStream_t stream) {
    const float* ref = (const float*)d_in[0];
    const float* tgt = (const float*)d_in[1];
    float* out = (float*)d_out;

    char* ws = (char*)d_ws;
    double* acc = (double*)ws;                                    // 32*4 doubles
    uchar* Mo = (uchar*)(ws + 2048);                              // 8 MB prox bytes
    float* lum = (float*)(ws + 2048 + (size_t)NIMG * NPIX);       // 32 MB

    // Gate the cooperative path on the runtime's own co-residency model
    // (stream-independent query — capture-safe). Only launch cooperatively
    // if 1280 blocks are guaranteed co-resident; otherwise use the verified
    // 3-dispatch path. Never issue a failing API call into the capture.
    int maxBlk = 0;
    hipError_t qe = hipOccupancyMaxActiveBlocksPerMultiprocessor(
        &maxBlk, (const void*)k_fused, 256, 0);
    bool coop_ok = (qe == hipSuccess) && (maxBlk >= 5);

    if (coop_ok) {
        void* args[] = {(void*)&ref, (void*)&tgt, (void*)&out,
                        (void*)&lum, (void*)&Mo, (void*)&acc};
        hipError_t le = hipLaunchCooperativeKernel((const void*)k_fused,
                                                   dim3(NBLK), dim3(256),
                                                   args, 0, stream);
        if (le == hipSuccess) return;
    }

    // Fallback: proven round-0 structure (acc zeroing fused into k_lum,
    // flags fused into k_out — 3 dispatches, no memset).
    k_lum<<<2048, 256, 0, stream>>>(ref, tgt, lum, acc);
    k_strip<<<NBLK, 256, 0, stream>>>(lum, Mo, acc);
    k_out<<<2048, 256, 0, stream>>>(Mo, acc, out);
}

// Round 4
// 217.828 us; speedup vs baseline: 1.2459x; 1.0385x over previous
//
#include <hip/hip_runtime.h>

#define HH 512
#define WW 512
#define NPIX (HH*WW)      // 2^18
#define BATCH 16
#define NIMG 32           // 16 ref + 16 tgt

typedef unsigned char uchar;
typedef unsigned long long u64;

__inline__ __device__ float wave_reduce(float v) {
#pragma unroll
    for (int o = 32; o > 0; o >>= 1) v += __shfl_down(v, o);
    return v;
}

// ---------------- Stage 1: luminance (one-shot, float4) + acc zeroing ------
// Round-0 verified structure (one float4-triple per thread, 8192 blocks);
// acc zeroing folded in (replaces hipMemsetAsync).
__global__ __launch_bounds__(256) void k_lum(const float4* __restrict__ ref,
                                             const float4* __restrict__ tgt,
                                             float4* __restrict__ lum,
                                             double* __restrict__ acc) {
    int idx = blockIdx.x * 256 + threadIdx.x;     // NIMG * NPIX/4 threads
    if (idx < NIMG * 4) acc[idx] = 0.0;
    int img = idx >> 16;                          // NPIX/4 = 65536
    int p4 = idx & 65535;
    const float4* src = (img < BATCH) ? (ref + (size_t)img * 3 * 65536)
                                      : (tgt + (size_t)(img - BATCH) * 3 * 65536);
    float4 r = src[p4];
    float4 g = src[65536 + p4];
    float4 b = src[131072 + p4];
    float4 o;
    o.x = 0.299f * r.x + 0.587f * g.x + 0.114f * b.x;
    o.y = 0.299f * r.y + 0.587f * g.y + 0.114f * b.y;
    o.z = 0.299f * r.z + 0.587f * g.z + 0.114f * b.z;
    o.w = 0.299f * r.w + 0.587f * g.w + 0.114f * b.w;
    lum[idx] = o;
}

// ---- Stages 2+3+4: barrier-free wave-pipelined strip kernel ----
// One wave = 52 output cols x 32 output rows. Rolling register pipeline over
// rows with depth-2 global prefetch of the lum buffer. NEW: the 7x7 masked
// moment sums are computed as per-lane sliding-window sums (3 shfl + 4 add
// per quantity) instead of ballot-broadcast taps (7x cndmask+add per
// accumulator) — ~42 fewer VALU ops per row, moved onto the idle LDS pipe.
__global__ __launch_bounds__(256) void k_strip(const float* __restrict__ lum,
                                               uchar* __restrict__ Mo_g,
                                               double* __restrict__ acc) {
    int lane = threadIdx.x & 63;
    int gw = blockIdx.x * 4 + (threadIdx.x >> 6);   // 0..5119
    int img = gw / 160;                             // 10 sx * 16 sy
    int rem = gw - img * 160;
    int sy = rem / 10;
    int sx = rem - sy * 10;
    int r0 = sy << 5;          // first output row
    int c0 = sx * 52;
    int col = c0 + lane - 6;
    bool colok = (unsigned)col < WW;

    // precomputed clamped shuffle source lanes
    int lm1 = (lane > 0) ? lane - 1 : 0;
    int lp1 = (lane < 63) ? lane + 1 : 63;
    int lp2 = (lane < 62) ? lane + 2 : 63;
    int lm3 = (lane > 2) ? lane - 3 : 0;

    const float* Lp = lum + (size_t)img * NPIX;
    uchar* Mo = Mo_g + (size_t)img * NPIX;

    // rolling lum triples: slot0=oldest(L-3) .. slot3=newest(L)
    float tm0 = 0, tm1 = 0, tm2 = 0, tm3 = 0;
    float tc0 = 0, tc1 = 0, tc2 = 0, tc3 = 0;
    float tp0 = 0, tp1 = 0, tp2 = 0, tp3 = 0;
    unsigned eb = 0, hb = 0, pbm = 0, vbm = 0;

    // ---- explicit prefetch pipeline (depth 2) ----
    float preA = (((unsigned)(r0 - 6) < HH) && colok) ? Lp[(size_t)(r0 - 6) * WW + col] : 0.0f;
    float preB = (((unsigned)(r0 - 5) < HH) && colok) ? Lp[(size_t)(r0 - 5) * WW + col] : 0.0f;

#define LOADROW(Lr) { \
    tm0 = tm1; tc0 = tc1; tp0 = tp1; \
    tm1 = tm2; tc1 = tc2; tp1 = tp2; \
    tm2 = tm3; tc2 = tc3; tp2 = tp3; \
    float ln = preA; preA = preB; \
    { int rr = (Lr) + 2; \
      preB = (((unsigned)rr < HH) && colok) ? Lp[(size_t)rr * WW + col] : 0.0f; } \
    tc3 = ln; tm3 = __shfl(ln, lm1); tp3 = __shfl(ln, lp1); }

#define SOBEL_E(Lr) { \
    float gx = (tp1 - tm1) + 2.0f * (tp2 - tm2) + (tp3 - tm3); \
    float gy = (tm3 + 2.0f * tc3 + tp3) - (tm1 + 2.0f * tc1 + tp1); \
    float grad = sqrtf(gx * gx + gy * gy + 1e-12f); \
    bool e = (grad > 0.1f) && colok && ((unsigned)((Lr) - 1) < HH); \
    u64 ebal = __ballot(e); \
    eb = (eb << 1) | (e ? 1u : 0u); \
    unsigned hE5 = (unsigned)((ebal << 2) >> lane) & 0x1Fu; \
    hb = (hb << 1) | (hE5 ? 1u : 0u); }

// sliding 7-window sum centered at lane: out[l] = sum_{k=l-3..l+3} yv[k]
// a = yv[l]+yv[l+1]; b = yv[l..l+3]; out = b + b[l-3] - yv[l]
#define SLIDE7(yv, out) { \
    float a_ = (yv) + __shfl((yv), lp1); \
    float b_ = a_ + __shfl(a_, lp2); \
    out = b_ + __shfl(b_, lm3) - (yv); }

    // ---- pre-roll: rows r0-6, r0-5 ----
    for (int q = 0; q < 2; ++q) { int Lr = r0 - 6 + q; LOADROW(Lr); }
    // ---- warm: rows r0-4..r0-1 (E/hE only) ----
    for (int q = 0; q < 4; ++q) { int Lr = r0 - 4 + q; LOADROW(Lr); SOBEL_E(Lr); }

    // ---- steady: 42 iterations, ring unrolled x7 ----
    float r1p[7], r2p[7], r1v[7], r2v[7];
    unsigned rcn[7];
    unsigned cnt_acc = 0;
    float a1p = 0, a2p = 0, a1v = 0, a2v = 0;
    float c0a = 0, c1a = 0, c2a = 0, c3a = 0;

    for (int o6 = 0; o6 < 6; ++o6) {
#pragma unroll
        for (int u = 0; u < 7; ++u) {
            int j = o6 * 7 + u;
            int Lr = r0 + j;
            LOADROW(Lr);
            SOBEL_E(Lr);
            int m = Lr - 3;
            bool ed = (hb & 0x1Fu) != 0;
            bool e3 = ((eb >> 2) & 1u) != 0;
            bool mrowok = (unsigned)m < HH;
            bool pp = ed && !e3 && mrowok && colok;
            bool vv = (!ed) && mrowok && colok;
            u64 pb = __ballot(pp);
            u64 vb = __ballot(vv);
            pbm = (pbm << 1) | (pp ? 1u : 0u);
            vbm = (vbm << 1) | (vv ? 1u : 0u);

            // per-lane masked moments for row m (x = this lane's col value)
            float x = tc0;
            float xq = x * x;
            float y1p = pp ? x  : 0.0f;
            float y2p = pp ? xq : 0.0f;
            float y1v = vv ? x  : 0.0f;
            float y2v = vv ? xq : 0.0f;
            float s1p, s2p, s1v, s2v;
            SLIDE7(y1p, s1p)
            SLIDE7(y2p, s2p)
            SLIDE7(y1v, s1v)
            SLIDE7(y2v, s2v)

            // window counts from the ballots (as before)
            unsigned pw = (unsigned)((pb << 3) >> lane) & 0x7Fu;
            unsigned vw = (unsigned)((vb << 3) >> lane) & 0x7Fu;
            unsigned cnt_new = (unsigned)__popc(pw) | ((unsigned)__popc(vw) << 8);

            if (j >= 7) {   // slide out row m-7
                cnt_acc -= rcn[u];
                a1p -= r1p[u]; a2p -= r2p[u]; a1v -= r1v[u]; a2v -= r2v[u];
            }
            cnt_acc += cnt_new;
            a1p += s1p; a2p += s2p; a1v += s1v; a2v += s2v;
            rcn[u] = cnt_new; r1p[u] = s1p; r2p[u] = s2p; r1v[u] = s1v; r2v[u] = s2v;

            if (j >= 3 && j <= 34) {   // write prox byte for owned row m
                if (lane >= 6 && lane <= 57 && colok)
                    Mo[(size_t)m * WW + col] = (uchar)(pp ? 1 : 0);
            }
            if (j >= 6 && j <= 37) {   // output row y = Lr-6
                float mp0 = (float)((pbm >> 3) & 1u);
                float mb0 = (float)((vbm >> 3) & 1u);
                if (lane < 6 || lane > 57) { mp0 = 0.0f; mb0 = 0.0f; }
                float cpf = (float)(cnt_acc & 0xFFu);
                float cvf = (float)((cnt_acc >> 8) & 0xFFu);
                float rCp = __builtin_amdgcn_rcpf(fmaxf(cpf, 1.0f));
                float meanp = a1p * rCp;
                float varp = fmaxf(a2p * rCp - meanp * meanp, 0.0f);
                float rCb = __builtin_amdgcn_rcpf(fmaxf(cvf, 1.0f));
                float meanb = a1v * rCb;
                float varb = fmaxf(a2v * rCb - meanb * meanb, 0.0f);
                c0a += varp * mp0; c1a += mp0;
                c2a += varb * mb0; c3a += mb0;
            }
        }
    }
#undef LOADROW
#undef SOBEL_E
#undef SLIDE7

    c0a = wave_reduce(c0a); c1a = wave_reduce(c1a);
    c2a = wave_reduce(c2a); c3a = wave_reduce(c3a);
    if (lane == 0) {
        atomicAdd(&acc[img * 4 + 0], (double)c0a);
        atomicAdd(&acc[img * 4 + 1], (double)c1a);
        atomicAdd(&acc[img * 4 + 2], (double)c2a);
        atomicAdd(&acc[img * 4 + 3], (double)c3a);
    }
}

// ---------------- Stage 5: output with fused flags (round-1 verified) ------
__global__ __launch_bounds__(256) void k_out(const uchar4* __restrict__ M,
                                             const double* __restrict__ acc,
                                             float4* __restrict__ out) {
    __shared__ float sf[2];
    int idx = blockIdx.x * 256 + threadIdx.x;   // BATCH * NPIX/4 threads
    int b = idx >> 16;                          // constant within a block
    if (threadIdx.x == 0) {
        const double* a = acc + (size_t)b * 4;
        double vp = a[0] / fmax(a[1], 1.0);
        double vb = a[2] / fmax(a[3], 1.0);
        sf[0] = ((vp / (vb + 1e-12)) > 2.0) ? 1.0f : 0.0f;
        const double* a2 = acc + (size_t)(b + BATCH) * 4;
        double vp2 = a2[0] / fmax(a2[1], 1.0);
        double vb2 = a2[2] / fmax(a2[3], 1.0);
        sf[1] = ((vp2 / (vb2 + 1e-12)) > 2.0) ? 1.0f : 0.0f;
    }
    __syncthreads();
    float fr = sf[0], ft = sf[1];
    int p = idx & 65535;
    uchar4 mr = M[(size_t)b * 65536 + p];
    uchar4 mt = M[(size_t)(b + BATCH) * 65536 + p];
    float4 o;
    o.x = fmaxf((mt.x ? ft : 0.0f) - (mr.x ? fr : 0.0f), 0.0f);
    o.y = fmaxf((mt.y ? ft : 0.0f) - (mr.y ? fr : 0.0f), 0.0f);
    o.z = fmaxf((mt.z ? ft : 0.0f) - (mr.z ? fr : 0.0f), 0.0f);
    o.w = fmaxf((mt.w ? ft : 0.0f) - (mr.w ? fr : 0.0f), 0.0f);
    out[idx] = o;
}

extern "C" void kernel_launch(void* const* d_in, const int* in_sizes, int n_in,
                              void* d_out, int out_size, void* d_ws, size_t ws_size,
                              hipStream_t stream) {
    const float* ref = (const float*)d_in[0];
    const float* tgt = (const float*)d_in[1];
    float* out = (float*)d_out;

    char* ws = (char*)d_ws;
    double* acc = (double*)ws;                                 // 32*4 doubles
    uchar* Mo = (uchar*)(ws + 2048);                           // 8 MB prox bytes
    float* lum = (float*)(ws + 2048 + (size_t)NIMG * NPIX);    // 32 MB

    int nAll = NIMG * NPIX;          // 8388608
    k_lum<<<nAll / 4 / 256, 256, 0, stream>>>((const float4*)ref, (const float4*)tgt,
                                              (float4*)lum, acc);
    k_strip<<<1280, 256, 0, stream>>>(lum, Mo, acc);   // 5120 waves
    k_out<<<BATCH * NPIX / 4 / 256, 256, 0, stream>>>((const uchar4*)Mo, acc, (float4*)out);
}